// Round 3
// baseline (45.796 us; speedup 1.0000x reference)
//
#include <hip/hip_runtime.h>

#define NX 4096
#define NY 2048
#define EPS 1e-8f
#define ROWS 8          // output rows per wave strip
#define CPW 63          // output columns per block (64 faces per wave)
#define BROWS 32        // output rows per block (4 waves)
#define TILE_ROWS 38    // BROWS + 6 halo
#define TILE_COLS 70    // 69 needed (CPW+7), padded to 70
#define LSTRIDE 70
#define INV_D 0.001f

__device__ __forceinline__ int clampi(int i, int lo, int hi) {
    return i < lo ? lo : (i > hi ? hi : i);
}

// One-divide WENO5 (weights scaled by (t1*t2*t3)^2; single fast rcp).
__device__ __forceinline__ float weno5(float qm2, float qm1, float q0, float qp1, float qp2) {
    const float f1 = fmaf(1.0f/3.0f, qm2, fmaf(-7.0f/6.0f, qm1, (11.0f/6.0f)*q0));
    const float f2 = fmaf(-1.0f/6.0f, qm1, fmaf(5.0f/6.0f, q0, (1.0f/3.0f)*qp1));
    const float f3 = fmaf(1.0f/3.0f, q0, fmaf(5.0f/6.0f, qp1, (-1.0f/6.0f)*qp2));
    const float k1 = 13.0f/12.0f, k2 = 0.25f;
    float d1 = qm2 - 2.0f*qm1 + q0;
    float e1 = qm2 - 4.0f*qm1 + 3.0f*q0;
    float d2 = qm1 - 2.0f*q0 + qp1;
    float e2 = qm1 - qp1;
    float d3 = q0 - 2.0f*qp1 + qp2;
    float e3 = 3.0f*q0 - 4.0f*qp1 + qp2;
    float b1 = fmaf(k1, d1*d1, k2*(e1*e1));
    float b2 = fmaf(k1, d2*d2, k2*(e2*e2));
    float b3 = fmaf(k1, d3*d3, k2*(e3*e3));
    float t1 = b1 + EPS, t2 = b2 + EPS, t3 = b3 + EPS;
    float p23 = t2*t3, p13 = t1*t3, p12 = t1*t2;
    float w1 = 0.1f*(p23*p23);
    float w2 = 0.6f*(p13*p13);
    float w3 = 0.3f*(p12*p12);
    float num = fmaf(w1, f1, fmaf(w2, f2, w3*f3));
    float den = (w1 + w2) + w3;
    return num * __builtin_amdgcn_rcpf(den);
}

// Face between cells i and i+1; hm2..hp3 = h at cells i-2 .. i+3; vel = u[i].
__device__ __forceinline__ float face_flux(float vel, float hm2, float hm1, float h0,
                                           float hp1, float hp2, float hp3) {
    bool pos = (vel >= 0.0f);
    float a = pos ? hm2 : hp3;
    float b = pos ? hm1 : hp2;
    float c = pos ? h0  : hp1;
    float d = pos ? hp1 : h0;
    float e = pos ? hp2 : hm1;
    return vel * weno5(a, b, c, d, e);
}

__global__ __launch_bounds__(256) void adv_kernel(const float* __restrict__ h,
                                                  const float* __restrict__ u,
                                                  const float* __restrict__ v,
                                                  float* __restrict__ out) {
    __shared__ float lds[TILE_ROWS * LSTRIDE];

    const int lane = threadIdx.x & 63;
    const int wid  = threadIdx.x >> 6;
    const int x0 = blockIdx.x * CPW;            // first output column
    const int y0 = blockIdx.y * BROWS;          // first output row of block
    const int y0w = y0 + wid * ROWS;            // first output row of this wave

    // ---- stage h tile into LDS with edge clamping baked in.
    // LDS (ly, lc) holds h[clamp(y0-3+ly)][clamp(x0-3+lc)].
    {
        int gx1 = clampi(x0 - 3 + lane, 0, NX - 1);
        int gx2 = clampi(x0 + 61 + lane, 0, NX - 1);   // lc = 64 + lane (lane<6)
        for (int ly = wid; ly < TILE_ROWS; ly += 4) {
            int gy = clampi(y0 - 3 + ly, 0, NY - 1);
            const float* hrow = h + (size_t)gy * NX;
            lds[ly * LSTRIDE + lane] = hrow[gx1];
            if (lane < 6) lds[ly * LSTRIDE + 64 + lane] = hrow[gx2];
        }
    }
    __syncthreads();

    const int xf = x0 - 1 + lane;               // x-face this lane computes
    const int xo = x0 + lane;                   // output column (lanes 0..62)
    const int xc = xo < NX ? xo : NX - 1;       // column for v loads
    const int xq = clampi(xf, 0, NX - 1);       // column for u loads

    // ---- y-direction faces: column xc, values from LDS.
    float w[ROWS + 6];
#pragma unroll
    for (int k = 0; k < ROWS + 6; ++k)
        w[k] = lds[(wid * ROWS + k) * LSTRIDE + lane + 3];

    float fn[ROWS + 1];
#pragma unroll
    for (int j = 0; j <= ROWS; ++j) {
        int fy = clampi(y0w - 1 + j, 0, NY - 1);
        float vv = v[(size_t)fy * NX + xc];
        fn[j] = face_flux(vv, w[j], w[j+1], w[j+2], w[j+3], w[j+4], w[j+5]);
    }

    // ---- per row: one x-face per lane from LDS, neighbor via shuffle.
#pragma unroll
    for (int r = 0; r < ROWS; ++r) {
        int y = y0w + r;
        const float* lrow = &lds[(wid * ROWS + r + 3) * LSTRIDE + lane];
        float fe = face_flux(u[(size_t)y * NX + xq],
                             lrow[0], lrow[1], lrow[2], lrow[3], lrow[4], lrow[5]);
        float fe_right = __shfl_down(fe, 1);    // face at column xo
        if (lane < CPW && xo < NX) {
            float val = 0.0f;
            if (xo >= 2 && xo < NX - 2 && y >= 2 && y < NY - 2) {
                val = -((fe_right - fe) + (fn[r + 1] - fn[r])) * INV_D;
            }
            out[(size_t)y * NX + xo] = val;
        }
    }
}

extern "C" void kernel_launch(void* const* d_in, const int* in_sizes, int n_in,
                              void* d_out, int out_size, void* d_ws, size_t ws_size,
                              hipStream_t stream) {
    const float* h = (const float*)d_in[0];
    const float* u = (const float*)d_in[1];
    const float* v = (const float*)d_in[2];
    float* out = (float*)d_out;

    dim3 block(256, 1, 1);
    dim3 grid((NX + CPW - 1) / CPW, NY / BROWS, 1);  // 66 x 64
    adv_kernel<<<grid, block, 0, stream>>>(h, u, v, out);
}